// Round 10
// baseline (163.885 us; speedup 1.0000x reference)
//
#include <hip/hip_runtime.h>
#include <math.h>

// ---------------------------------------------------------------------------
// ConvLogicNetCIFAR forward. R10 = R9 pair-sync structure + R7 stage quality.
// 256 blocks x 1024 thr = 128 groups x 2 blocks (pair b <-> b^128, same XCD
// under %8 round-robin). Group owns batch elem g; activations in GLOBAL (L2)
// using R7's pair-duplicated padded h2 geometry: cell (c,i,j) = (v[i][j],
// v[i][j+1]), halo zero -> no bounds checks, one 4B load feeds both pooled
// columns, packed v_pk_fma_f16 gate math (2 positions/op). DISJOINT per-stage
// regions so halos are zeroed once (phase 0, fused with binarize -- no extra
// sync). Per-thread fixed output channel -> leaf/coef hoisted out of the
// position loop (R9 re-decoded every iteration: ~4.7x VALU bloat).
// 5 agent-scope release/acquire pair barriers (grid.sync costs ~40us, R8).
// Prep (softmax coefs + FC tree + flag zero) stays a separate small dispatch.
// Gate: c0 + c1*a + c2*b + c3*(a*b), c = softmax(w_row)@COEF.
// Conv tree quirk: off=2^lvl-1 -> level0 rows0..3, level1 rows1..2, level2 row3.
// ---------------------------------------------------------------------------

typedef _Float16 h16;
typedef _Float16 h2 __attribute__((ext_vector_type(2)));

__constant__ float c_coef_tbl[16][4] = {
    {0, 0, 0, 0}, {0, 0, 0, 1}, {0, 1, 0, -1}, {0, 1, 0, 0},
    {0, 0, 1, -1}, {0, 0, 1, 0}, {0, 1, 1, -2}, {0, 1, 1, -1},
    {1, -1, -1, 1}, {1, -1, -1, 2}, {1, 0, -1, 0}, {1, 0, -1, 1},
    {1, -1, 0, 0}, {1, -1, 0, 1}, {1, 0, 0, -1}, {1, 0, 0, 0}};

__device__ __forceinline__ float4 softmax_coef(const float* __restrict__ wr) {
  float m = -1e30f;
#pragma unroll
  for (int k = 0; k < 16; ++k) m = fmaxf(m, wr[k]);
  float e[16], s = 0.f;
#pragma unroll
  for (int k = 0; k < 16; ++k) { e[k] = __expf(wr[k] - m); s += e[k]; }
  float inv = 1.f / s;
  float c0 = 0.f, c1 = 0.f, c2 = 0.f, c3 = 0.f;
#pragma unroll
  for (int k = 0; k < 16; ++k) {
    c0 += e[k] * c_coef_tbl[k][0];
    c1 += e[k] * c_coef_tbl[k][1];
    c2 += e[k] * c_coef_tbl[k][2];
    c3 += e[k] * c_coef_tbl[k][3];
  }
  return make_float4(c0 * inv, c1 * inv, c2 * inv, c3 * inv);
}

__device__ __forceinline__ float gate_eval(float4 c, float a, float b) {
  return c.x + c.y * a + c.z * b + c.w * (a * b);
}
__device__ __forceinline__ float4 dec_cf(uint2 u) {
  h2 p0, p1;
  *(unsigned*)&p0 = u.x;
  *(unsigned*)&p1 = u.y;
  return make_float4((float)p0[0], (float)p0[1], (float)p1[0], (float)p1[1]);
}
__device__ __forceinline__ h2 gateh(const h2* c, h2 a, h2 b) {
  return c[0] + c[1] * a + c[2] * b + c[3] * (a * b);
}

// prep: g<71680 FC tree (o=g/7, s=g%7 -> fp16 coefs, u16 midx);
// [71680,78464) conv gate coefs float4; g<256 zeroes sync flags.
__global__ void prep_all(const float* __restrict__ w1, const float* __restrict__ w2,
                         const float* __restrict__ w3, const float* __restrict__ w4,
                         const float* __restrict__ fw1, const float* __restrict__ fw2,
                         const float* __restrict__ fw3,
                         const int* __restrict__ ca1, const int* __restrict__ cb1,
                         const int* __restrict__ ca2, const int* __restrict__ cb2,
                         const int* __restrict__ ca3, const int* __restrict__ cb3,
                         float4* __restrict__ coefC,
                         unsigned short* __restrict__ midx16,
                         _Float16* __restrict__ mcoefh,
                         unsigned int* __restrict__ flags) {
  int g = blockIdx.x * blockDim.x + threadIdx.x;
  if (g < 256) flags[g] = 0u;
  if (g < 71680) {
    int o = g / 7;
    int s = g - o * 7;
    float4 c;
    if (s < 4) {
      int k = (s < 2) ? ca3[o] : cb3[o];
      int j = (s & 1) ? cb2[k] : ca2[k];
      midx16[o * 8 + s * 2]     = (unsigned short)ca1[j];
      midx16[o * 8 + s * 2 + 1] = (unsigned short)cb1[j];
      c = softmax_coef(fw1 + j * 16);
    } else if (s < 6) {
      int k = (s == 4) ? ca3[o] : cb3[o];
      c = softmax_coef(fw2 + k * 16);
    } else {
      c = softmax_coef(fw3 + o * 16);
    }
    _Float16* mc = mcoefh + o * 28 + s * 4;
    mc[0] = (_Float16)c.x; mc[1] = (_Float16)c.y;
    mc[2] = (_Float16)c.z; mc[3] = (_Float16)c.w;
  } else if (g < 78464) {
    int gg = g - 71680;
    int base = gg;
    const float* w;
    if (gg < 128)       {             w = w1; }
    else if (gg < 640)  { gg -= 128;  w = w2; }
    else if (gg < 2688) { gg -= 640;  w = w3; }
    else                { gg -= 2688; w = w4; }
    coefC[base] = softmax_coef(w + ((gg >> 2) * 7 + (gg & 3)) * 16);
  }
}

// pair barrier: release my flag=s, spin until partner flag >= s.
__device__ __forceinline__ void psync(unsigned int* flags, int me, int pa,
                                      unsigned int s, int tid) {
  __syncthreads();
  if (tid == 0) {
    __threadfence();
    __hip_atomic_store(&flags[me], s, __ATOMIC_RELEASE, __HIP_MEMORY_SCOPE_AGENT);
    while (__hip_atomic_load(&flags[pa], __ATOMIC_ACQUIRE,
                             __HIP_MEMORY_SCOPE_AGENT) < s) {
      __builtin_amdgcn_s_sleep(2);
    }
  }
  __syncthreads();
}

// One conv_tree+orpool stage for this block's half of the output channels.
// in: [C][H+2][W+2] h2 cells (global). DUP out: [OC][PH+2][PW+2] h2 cells;
// else plain fp16 [OC][PH][PW]. Per-thread oc fixed -> taps/coefs hoisted.
template <int C, int H, int W, int OC, bool DUP>
__device__ void stage(const h2* __restrict__ in, h2* __restrict__ outD,
                      h16* __restrict__ outP,
                      const int* __restrict__ leaf,
                      const float4* __restrict__ coef, int role, int tid) {
  constexpr int Hp = H + 2, Wp = W + 2;
  constexpr int PH = H / 2, PW = W / 2;
  constexpr int NPOS = PH * PW;
  constexpr int TPO = 2048 / OC;   // threads per oc (half the channels/block)
  constexpr int ITER = NPOS / TPO;
  constexpr int OWp = PW + 2;
  constexpr int OHWp = (PH + 2) * (PW + 2);

  int oc = role * (OC / 2) + tid / TPO;
  int lane = tid % TPO;

  int toff[8];
#pragma unroll
  for (int l = 0; l < 8; ++l) {
    int k = leaf[oc * 8 + l];
    int cc = k / 9;
    int p = k - 9 * cc;
    int di = p / 3;
    int dj = p - 3 * di;
    toff[l] = cc * (Hp * Wp) + di * Wp + dj;
  }
  h2 ch[4][4];
#pragma unroll
  for (int r = 0; r < 4; ++r) {
    float4 c = coef[oc * 4 + r];
    _Float16 x0 = (_Float16)c.x, x1 = (_Float16)c.y,
             x2 = (_Float16)c.z, x3 = (_Float16)c.w;
    ch[r][0][0] = x0; ch[r][0][1] = x0;
    ch[r][1][0] = x1; ch[r][1][1] = x1;
    ch[r][2][0] = x2; ch[r][2][1] = x2;
    ch[r][3][0] = x3; ch[r][3][1] = x3;
  }

#pragma unroll
  for (int it = 0; it < ITER; ++it) {
    int pos = lane + it * TPO;
    int pw = pos % PW, ph = pos / PW;
    h2 o01[2];
#pragma unroll
    for (int py = 0; py < 2; ++py) {
      int pbase = (2 * ph + py) * Wp + 2 * pw;
      h2 lv[8];
#pragma unroll
      for (int l = 0; l < 8; ++l) lv[l] = in[toff[l] + pbase];
      h2 t0 = gateh(ch[0], lv[0], lv[1]);
      h2 t1 = gateh(ch[1], lv[2], lv[3]);
      h2 t2 = gateh(ch[2], lv[4], lv[5]);
      h2 t3 = gateh(ch[3], lv[6], lv[7]);
      h2 u0 = gateh(ch[1], t0, t1);
      h2 u1 = gateh(ch[2], t2, t3);
      o01[py] = gateh(ch[3], u0, u1);
    }
    _Float16 m0 = o01[0][0] > o01[1][0] ? o01[0][0] : o01[1][0];
    _Float16 m1 = o01[0][1] > o01[1][1] ? o01[0][1] : o01[1][1];
    _Float16 v = m0 > m1 ? m0 : m1;
    if (DUP) {
      h16* oh = (h16*)outD;
      int cell = oc * OHWp + (ph + 1) * OWp + (pw + 1);
      oh[2 * cell] = v;      // lo of (ph+1, pw+1)
      oh[2 * cell - 1] = v;  // hi of (ph+1, pw)
    } else {
      outP[oc * NPOS + ph * PW + pw] = v;
    }
  }
}

__global__ __launch_bounds__(1024) void coop(
    const float* __restrict__ x, const float4* __restrict__ coefC,
    const int* __restrict__ l1, const int* __restrict__ l2,
    const int* __restrict__ l3, const int* __restrict__ l4,
    const unsigned short* __restrict__ midx16,
    const _Float16* __restrict__ mcoefh,
    h2* __restrict__ xbB, h2* __restrict__ s1B, h2* __restrict__ s2B,
    h2* __restrict__ s3B, h16* __restrict__ s4B,
    unsigned int* __restrict__ flags, float* __restrict__ out) {
  __shared__ float red[16];
  int tid = threadIdx.x;
  int me = blockIdx.x;
  int g = me & 127;
  int role = me >> 7;
  int pa = me ^ 128;

  const float* xg = x + g * 3072;
  h2*  xb = xbB + g * 10404;  // [9][34][34]
  h2*  b1 = s1B + g * 10368;  // [32][18][18]
  h2*  b2 = s2B + g * 12800;  // [128][10][10]
  h2*  b3 = s3B + g * 18432;  // [512][6][6]
  h16* b4 = s4B + g * 4096;   // [1024][2][2] plain

  // ---- phase 0: zero s1/s2/s3 (disjoint regions -> halos stay clean) ----
  {
    float4* z1 = (float4*)b1;  // 10368*4/16 = 2592
    float4* z2 = (float4*)b2;  // 3200
    float4* z3 = (float4*)b3;  // 4608
    float4 zz = make_float4(0.f, 0.f, 0.f, 0.f);
    for (int i = role * 1296 + tid; i < (role + 1) * 1296; i += 1024) z1[i] = zz;
    for (int i = role * 1600 + tid; i < (role + 1) * 1600; i += 1024) z2[i] = zz;
    for (int i = role * 2304 + tid; i < (role + 1) * 2304; i += 1024) z3[i] = zz;
  }
  // ---- phase 0b: binarize -> xb dup-padded [9][34][34] (all cells) ----
  for (int cell = role * 5202 + tid; cell < role * 5202 + 5202; cell += 1024) {
    int j = cell % 34;
    int t = cell / 34;
    int i = t % 34;
    int c9 = t / 34;
    int th = c9 / 3, c = c9 - 3 * th;
    float thr = (float)(th + 1) * 0.25f;
    _Float16 lo = (_Float16)0, hi = (_Float16)0;
    if (i >= 1 && i <= 32) {
      const float* row = xg + c * 1024 + (i - 1) * 32;
      if (j >= 1 && j <= 32) lo = (_Float16)((row[j - 1] > thr) ? 1.f : 0.f);
      if (j <= 31)           hi = (_Float16)((row[j] > thr) ? 1.f : 0.f);
    }
    xb[cell] = h2{lo, hi};
  }
  psync(flags, me, pa, 1, tid);

  // ---- conv tower (each block: half the output channels) ----
  stage<9, 32, 32, 32, true>(xb, b1, nullptr, l1, coefC, role, tid);
  psync(flags, me, pa, 2, tid);
  stage<32, 16, 16, 128, true>(b1, b2, nullptr, l2, coefC + 128, role, tid);
  psync(flags, me, pa, 3, tid);
  stage<128, 8, 8, 512, true>(b2, b3, nullptr, l3, coefC + 640, role, tid);
  psync(flags, me, pa, 4, tid);
  stage<512, 4, 4, 1024, false>(b3, nullptr, b4, l4, coefC + 2688, role, tid);
  psync(flags, me, pa, 5, tid);

  // ---- FC: classes role*5 .. role*5+4; o = cls*1024 + tid ----
  const uint4* mi = (const uint4*)midx16;
  const uint2* mc = (const uint2*)mcoefh;
#pragma unroll
  for (int k = 0; k < 5; ++k) {
    int cls = role * 5 + k;
    int o = cls * 1024 + tid;
    uint4 I = mi[o];
    const uint2* cfp = mc + o * 7;
    float L0 = gate_eval(dec_cf(cfp[0]), (float)b4[I.x & 0xffff], (float)b4[I.x >> 16]);
    float L1 = gate_eval(dec_cf(cfp[1]), (float)b4[I.y & 0xffff], (float)b4[I.y >> 16]);
    float L2 = gate_eval(dec_cf(cfp[2]), (float)b4[I.z & 0xffff], (float)b4[I.z >> 16]);
    float L3 = gate_eval(dec_cf(cfp[3]), (float)b4[I.w & 0xffff], (float)b4[I.w >> 16]);
    float M0 = gate_eval(dec_cf(cfp[4]), L0, L1);
    float M1 = gate_eval(dec_cf(cfp[5]), L2, L3);
    float y = gate_eval(dec_cf(cfp[6]), M0, M1);
#pragma unroll
    for (int m = 32; m > 0; m >>= 1) y += __shfl_xor(y, m, 64);
    if ((tid & 63) == 0) red[tid >> 6] = y;
    __syncthreads();
    if (tid == 0) {
      float s = 0.f;
#pragma unroll
      for (int w = 0; w < 16; ++w) s += red[w];
      out[g * 10 + cls] = s * 0.1f;
    }
    __syncthreads();
  }
}

extern "C" void kernel_launch(void* const* d_in, const int* in_sizes, int n_in,
                              void* d_out, int out_size, void* d_ws, size_t ws_size,
                              hipStream_t stream) {
  const float* x   = (const float*)d_in[0];
  const float* w1  = (const float*)d_in[1];
  const float* w2  = (const float*)d_in[2];
  const float* w3  = (const float*)d_in[3];
  const float* w4  = (const float*)d_in[4];
  const float* fw1 = (const float*)d_in[5];
  const float* fw2 = (const float*)d_in[6];
  const float* fw3 = (const float*)d_in[7];
  const int* l1  = (const int*)d_in[8];
  const int* l2  = (const int*)d_in[9];
  const int* l3  = (const int*)d_in[10];
  const int* l4  = (const int*)d_in[11];
  const int* ca1 = (const int*)d_in[12];
  const int* cb1 = (const int*)d_in[13];
  const int* ca2 = (const int*)d_in[14];
  const int* cb2 = (const int*)d_in[15];
  const int* ca3 = (const int*)d_in[16];
  const int* cb3 = (const int*)d_in[17];
  float* out = (float*)d_out;

  char* ws = (char*)d_ws;
  float4*         coefC  = (float4*)ws;                    //        0 .. 108,544
  unsigned short* midx16 = (unsigned short*)(ws + 108544); //  +163,840
  _Float16*       mcoefh = (_Float16*)(ws + 272384);       //  +573,440
  unsigned int*   flags  = (unsigned int*)(ws + 845824);   //  +1,024
  h2*  xbB = (h2*)(ws + 846848);        // 128*10404*4 = 5,326,848
  h2*  s1B = (h2*)(ws + 6173696);       // 128*10368*4 = 5,308,416
  h2*  s2B = (h2*)(ws + 11482112);      // 128*12800*4 = 6,553,600
  h2*  s3B = (h2*)(ws + 18035712);      // 128*18432*4 = 9,437,184
  h16* s4B = (h16*)(ws + 27472896);     // 128*4096*2  = 1,048,576  (end ~28.5MB)

  prep_all<<<307, 256, 0, stream>>>(w1, w2, w3, w4, fw1, fw2, fw3,
                                    ca1, cb1, ca2, cb2, ca3, cb3,
                                    coefC, midx16, mcoefh, flags);

  void* args[] = {&x, &coefC, &l1, &l2, &l3, &l4, &midx16, &mcoefh,
                  &xbB, &s1B, &s2B, &s3B, &s4B, &flags, &out};
  hipLaunchCooperativeKernel((void*)coop, dim3(256), dim3(1024), args, 0, stream);
}

// Round 11
// 63.138 us; speedup vs baseline: 2.5957x; 2.5957x over previous
//
#include <hip/hip_runtime.h>
#include <math.h>

// ---------------------------------------------------------------------------
// ConvLogicNetCIFAR forward. R11 = R7 megakernel + barrier/conflict fixes.
// LESSON (R8/R9/R10): ANY cross-block sync costs an agent-scope fence =
// per-XCD L2 writeback/invalidate (R10: 46MB writebacks, 18MB refetch, time
// flat) -- grid.sync ~40us, pair-sync just as bad. And the conv pyramid's
// receptive field spans everything by stage 3, so a batch element cannot be
// split across blocks without sync. Structure: 128 blocks x 1024 thr, whole
// tower in LDS (R7 = 62.8us). This round optimizes within that:
//  - DISJOINT LDS regions (xb|s1|s2|s3|s4 = ~160KB, fits 160KiB/CU at the
//    same 1 block/CU occupancy) -> all halo zeroing folds into phase 0;
//    barriers 12 -> 6.
//  - ODD channel-plane strides (1157/325/101) to break even-stride LDS bank
//    aliasing (R7: 4.2M conflict cycles).
//  - s3/s4 plain fp16 (no halo pad, no dup): saves 57KB LDS + zero pass;
//    stage4 does bounds-checked scalar taps (cheap VALU).
// Pair-dup cells elsewhere: cell(c,i,j) = (v[i-1][j-1], v[i-1][j]) -> one
// 4B LDS read serves both pooled columns; packed v_pk_fma_f16 gates.
// Gate: c0 + c1*a + c2*b + c3*(a*b), c = softmax(w_row)@COEF.
// Conv tree quirk: off=2^lvl-1 -> level0 rows0..3, level1 rows1..2, level2 row3.
// ---------------------------------------------------------------------------

typedef _Float16 h16;
typedef _Float16 h2 __attribute__((ext_vector_type(2)));

__constant__ float c_coef_tbl[16][4] = {
    {0, 0, 0, 0}, {0, 0, 0, 1}, {0, 1, 0, -1}, {0, 1, 0, 0},
    {0, 0, 1, -1}, {0, 0, 1, 0}, {0, 1, 1, -2}, {0, 1, 1, -1},
    {1, -1, -1, 1}, {1, -1, -1, 2}, {1, 0, -1, 0}, {1, 0, -1, 1},
    {1, -1, 0, 0}, {1, -1, 0, 1}, {1, 0, 0, -1}, {1, 0, 0, 0}};

__device__ __forceinline__ float4 softmax_coef(const float* __restrict__ wr) {
  float m = -1e30f;
#pragma unroll
  for (int k = 0; k < 16; ++k) m = fmaxf(m, wr[k]);
  float e[16], s = 0.f;
#pragma unroll
  for (int k = 0; k < 16; ++k) { e[k] = __expf(wr[k] - m); s += e[k]; }
  float inv = 1.f / s;
  float c0 = 0.f, c1 = 0.f, c2 = 0.f, c3 = 0.f;
#pragma unroll
  for (int k = 0; k < 16; ++k) {
    c0 += e[k] * c_coef_tbl[k][0];
    c1 += e[k] * c_coef_tbl[k][1];
    c2 += e[k] * c_coef_tbl[k][2];
    c3 += e[k] * c_coef_tbl[k][3];
  }
  return make_float4(c0 * inv, c1 * inv, c2 * inv, c3 * inv);
}

__device__ __forceinline__ float gate_eval(float4 c, float a, float b) {
  return c.x + c.y * a + c.z * b + c.w * (a * b);
}
__device__ __forceinline__ float4 dec_cf(uint2 u) {
  h2 p0, p1;
  *(unsigned*)&p0 = u.x;
  *(unsigned*)&p1 = u.y;
  return make_float4((float)p0[0], (float)p0[1], (float)p1[0], (float)p1[1]);
}
__device__ __forceinline__ h2 gateh(const h2* c, h2 a, h2 b) {
  return c[0] + c[1] * a + c[2] * b + c[3] * (a * b);
}

// prep: g<71680 FC tree (o=g/7, s=g%7 -> fp16 coefs mcoefh[o*28+s*4], u16
// midx16[o*8..]); g in [71680,78464) conv gate coefs float4
// (w1[0,128) w2[128,640) w3[640,2688) w4[2688,6784); gate gg -> row oc*7+(gg&3)).
__global__ void prep_all(const float* __restrict__ w1, const float* __restrict__ w2,
                         const float* __restrict__ w3, const float* __restrict__ w4,
                         const float* __restrict__ fw1, const float* __restrict__ fw2,
                         const float* __restrict__ fw3,
                         const int* __restrict__ ca1, const int* __restrict__ cb1,
                         const int* __restrict__ ca2, const int* __restrict__ cb2,
                         const int* __restrict__ ca3, const int* __restrict__ cb3,
                         float4* __restrict__ coefC,
                         unsigned short* __restrict__ midx16,
                         _Float16* __restrict__ mcoefh) {
  int g = blockIdx.x * blockDim.x + threadIdx.x;
  if (g < 71680) {
    int o = g / 7;
    int s = g - o * 7;
    float4 c;
    if (s < 4) {
      int k = (s < 2) ? ca3[o] : cb3[o];
      int j = (s & 1) ? cb2[k] : ca2[k];
      midx16[o * 8 + s * 2]     = (unsigned short)ca1[j];
      midx16[o * 8 + s * 2 + 1] = (unsigned short)cb1[j];
      c = softmax_coef(fw1 + j * 16);
    } else if (s < 6) {
      int k = (s == 4) ? ca3[o] : cb3[o];
      c = softmax_coef(fw2 + k * 16);
    } else {
      c = softmax_coef(fw3 + o * 16);
    }
    _Float16* mc = mcoefh + o * 28 + s * 4;
    mc[0] = (_Float16)c.x; mc[1] = (_Float16)c.y;
    mc[2] = (_Float16)c.z; mc[3] = (_Float16)c.w;
  } else if (g < 78464) {
    int gg = g - 71680;
    int base = gg;
    const float* w;
    if (gg < 128)       {             w = w1; }
    else if (gg < 640)  { gg -= 128;  w = w2; }
    else if (gg < 2688) { gg -= 640;  w = w3; }
    else                { gg -= 2688; w = w4; }
    coefC[base] = softmax_coef(w + ((gg >> 2) * 7 + (gg & 3)) * 16);
  }
}

// Conv tree + orpool, LDS->LDS, dup-padded in; dup-padded (OUTDUP) or plain
// fp16 out.  IPS/OPS = channel-plane strides in cells (odd to spread banks).
template <int C, int H, int W, int OC, int IPS, int OPS, bool OUTDUP>
__device__ void stage(const h2* __restrict__ in, h2* __restrict__ outD,
                      h16* __restrict__ outP,
                      const int* __restrict__ leaf,
                      const float4* __restrict__ coef, int tid) {
  constexpr int Wp = W + 2;
  constexpr int PH = H / 2, PW = W / 2;
  constexpr int NPOS = PH * PW;
  constexpr int TPO = 1024 / OC;
  constexpr int ITER = NPOS / TPO;
  constexpr int OWp = PW + 2;

  int oc = tid / TPO;
  int lane = tid % TPO;

  int toff[8];
#pragma unroll
  for (int l = 0; l < 8; ++l) {
    int k = leaf[oc * 8 + l];
    int cc = k / 9;
    int p = k - 9 * cc;
    int di = p / 3;
    int dj = p - 3 * di;
    toff[l] = cc * IPS + di * Wp + dj;
  }
  h2 ch[4][4];
#pragma unroll
  for (int r = 0; r < 4; ++r) {
    float4 c = coef[oc * 4 + r];
    _Float16 x0 = (_Float16)c.x, x1 = (_Float16)c.y,
             x2 = (_Float16)c.z, x3 = (_Float16)c.w;
    ch[r][0][0] = x0; ch[r][0][1] = x0;
    ch[r][1][0] = x1; ch[r][1][1] = x1;
    ch[r][2][0] = x2; ch[r][2][1] = x2;
    ch[r][3][0] = x3; ch[r][3][1] = x3;
  }

#pragma unroll
  for (int it = 0; it < ITER; ++it) {
    int pos = lane + it * TPO;
    int pw = pos % PW, ph = pos / PW;
    h2 o01[2];
#pragma unroll
    for (int py = 0; py < 2; ++py) {
      int pbase = (2 * ph + py) * Wp + 2 * pw;
      h2 lv[8];
#pragma unroll
      for (int l = 0; l < 8; ++l) lv[l] = in[toff[l] + pbase];
      h2 t0 = gateh(ch[0], lv[0], lv[1]);
      h2 t1 = gateh(ch[1], lv[2], lv[3]);
      h2 t2 = gateh(ch[2], lv[4], lv[5]);
      h2 t3 = gateh(ch[3], lv[6], lv[7]);
      h2 u0 = gateh(ch[1], t0, t1);
      h2 u1 = gateh(ch[2], t2, t3);
      o01[py] = gateh(ch[3], u0, u1);
    }
    _Float16 m0 = o01[0][0] > o01[1][0] ? o01[0][0] : o01[1][0];
    _Float16 m1 = o01[0][1] > o01[1][1] ? o01[0][1] : o01[1][1];
    _Float16 v = m0 > m1 ? m0 : m1;
    if (OUTDUP) {
      h16* oh = (h16*)outD;
      int cell = oc * OPS + (ph + 1) * OWp + (pw + 1);
      oh[2 * cell] = v;      // lo of (ph+1, pw+1)
      oh[2 * cell - 1] = v;  // hi of (ph+1, pw)
    } else {
      outP[oc * NPOS + ph * PW + pw] = v;
    }
  }
}

// Megakernel: one block per batch element, 128 blocks x 1024 threads.
__global__ __launch_bounds__(1024) void mega(
    const float* __restrict__ x, const float4* __restrict__ coefC,
    const int* __restrict__ l1, const int* __restrict__ l2,
    const int* __restrict__ l3, const int* __restrict__ l4,
    const unsigned short* __restrict__ midx16,
    const _Float16* __restrict__ mcoefh, float* __restrict__ out) {
  // disjoint LDS regions (fits 160KiB/CU; same 1-block/CU occupancy as R7)
  __shared__ __align__(16) h2 XB[9 * 1157];    // 41,652B  [9][34x34 +1]
  __shared__ __align__(16) h2 S1[32 * 325];    // 41,600B  [32][18x18 +1]
  __shared__ __align__(16) h2 S2[128 * 101];   // 51,712B  [128][10x10 +1]
  __shared__ __align__(16) h16 S3[512 * 16];   // 16,384B  plain [512][4][4]
  __shared__ __align__(16) h16 S4[1024 * 4];   //  8,192B  plain [1024][2][2]
  __shared__ float red[16][10];
  int tid = threadIdx.x;
  int b = blockIdx.x;

  // ---- phase 0: zero S1/S2 (halos incl.) + binarize x -> XB dup-padded ----
  {
    float4* z1 = (float4*)S1;  // 10400 h2 = 2600 float4
    float4* z2 = (float4*)S2;  // 12928 h2 = 3232 float4
    float4 zz = make_float4(0.f, 0.f, 0.f, 0.f);
    for (int i = tid; i < 2600; i += 1024) z1[i] = zz;
    for (int i = tid; i < 3232; i += 1024) z2[i] = zz;
  }
  const float* xg = x + b * 3072;
  for (int cell = tid; cell < 9 * 1157; cell += 1024) {
    int c9 = cell / 1157;
    int rem = cell - c9 * 1157;
    if (rem >= 1156) continue;  // plane pad cell, never read
    int i = rem / 34, j = rem - 34 * (rem / 34);
    int th = c9 / 3, c = c9 - 3 * th;
    float thr = (float)(th + 1) * 0.25f;
    _Float16 lo = (_Float16)0, hi = (_Float16)0;
    if (i >= 1 && i <= 32) {
      const float* row = xg + c * 1024 + (i - 1) * 32;
      if (j >= 1 && j <= 32) lo = (_Float16)((row[j - 1] > thr) ? 1.f : 0.f);
      if (j <= 31)           hi = (_Float16)((row[j] > thr) ? 1.f : 0.f);
    }
    XB[cell] = h2{lo, hi};
  }
  __syncthreads();

  // ---- conv tower ----
  stage<9, 32, 32, 32, 1157, 325, true>(XB, S1, nullptr, l1, coefC, tid);
  __syncthreads();
  stage<32, 16, 16, 128, 325, 101, true>(S1, S2, nullptr, l2, coefC + 128, tid);
  __syncthreads();
  stage<128, 8, 8, 512, 101, 0, false>(S2, nullptr, S3, l3, coefC + 640, tid);
  __syncthreads();

  // ---- stage 4: plain in [512][4][4] with bounds checks, 1 thread/oc ----
  {
    int oc = tid;
    int cc[8], di[8], dj[8];
#pragma unroll
    for (int l = 0; l < 8; ++l) {
      int k = l4[oc * 8 + l];
      cc[l] = k / 9;
      int p = k - 9 * cc[l];
      di[l] = p / 3;
      dj[l] = p - 3 * di[l];
    }
    float4 c0 = coefC[2688 + oc * 4 + 0];
    float4 c1 = coefC[2688 + oc * 4 + 1];
    float4 c2 = coefC[2688 + oc * 4 + 2];
    float4 c3 = coefC[2688 + oc * 4 + 3];
#pragma unroll
    for (int pos = 0; pos < 4; ++pos) {
      int pw = pos & 1, ph = pos >> 1;
      float best = -1e30f;
#pragma unroll
      for (int py = 0; py < 2; ++py) {
#pragma unroll
        for (int px = 0; px < 2; ++px) {
          int i = 2 * ph + py, j = 2 * pw + px;
          float lv[8];
#pragma unroll
          for (int l = 0; l < 8; ++l) {
            int ii = i + di[l] - 1, jj = j + dj[l] - 1;
            float v = 0.f;
            if ((unsigned)ii < 4u && (unsigned)jj < 4u)
              v = (float)S3[cc[l] * 16 + ii * 4 + jj];
            lv[l] = v;
          }
          float t0 = gate_eval(c0, lv[0], lv[1]);
          float t1 = gate_eval(c1, lv[2], lv[3]);
          float t2 = gate_eval(c2, lv[4], lv[5]);
          float t3 = gate_eval(c3, lv[6], lv[7]);
          float u0 = gate_eval(c1, t0, t1);
          float u1 = gate_eval(c2, t2, t3);
          best = fmaxf(best, gate_eval(c3, u0, u1));
        }
      }
      S4[oc * 4 + pos] = (h16)best;
    }
  }
  __syncthreads();

  // ---- fused FC, streamed; o = k*1024 + tid ----
  const uint4* mi = (const uint4*)midx16;
  const uint2* mc = (const uint2*)mcoefh;
  int wid = tid >> 6;
#pragma unroll
  for (int k = 0; k < 10; ++k) {
    int o = k * 1024 + tid;
    uint4 I = mi[o];
    const uint2* cfp = mc + o * 7;
    float L0 = gate_eval(dec_cf(cfp[0]), (float)S4[I.x & 0xffff], (float)S4[I.x >> 16]);
    float L1 = gate_eval(dec_cf(cfp[1]), (float)S4[I.y & 0xffff], (float)S4[I.y >> 16]);
    float L2 = gate_eval(dec_cf(cfp[2]), (float)S4[I.z & 0xffff], (float)S4[I.z >> 16]);
    float L3 = gate_eval(dec_cf(cfp[3]), (float)S4[I.w & 0xffff], (float)S4[I.w >> 16]);
    float M0 = gate_eval(dec_cf(cfp[4]), L0, L1);
    float M1 = gate_eval(dec_cf(cfp[5]), L2, L3);
    float y = gate_eval(dec_cf(cfp[6]), M0, M1);
#pragma unroll
    for (int m = 32; m > 0; m >>= 1) y += __shfl_xor(y, m, 64);
    if ((tid & 63) == 0) red[wid][k] = y;
  }
  __syncthreads();
  if (tid < 10) {
    float s = 0.f;
#pragma unroll
    for (int w = 0; w < 16; ++w) s += red[w][tid];
    out[b * 10 + tid] = s * 0.1f;
  }
}

extern "C" void kernel_launch(void* const* d_in, const int* in_sizes, int n_in,
                              void* d_out, int out_size, void* d_ws, size_t ws_size,
                              hipStream_t stream) {
  const float* x   = (const float*)d_in[0];
  const float* w1  = (const float*)d_in[1];
  const float* w2  = (const float*)d_in[2];
  const float* w3  = (const float*)d_in[3];
  const float* w4  = (const float*)d_in[4];
  const float* fw1 = (const float*)d_in[5];
  const float* fw2 = (const float*)d_in[6];
  const float* fw3 = (const float*)d_in[7];
  const int* l1  = (const int*)d_in[8];
  const int* l2  = (const int*)d_in[9];
  const int* l3  = (const int*)d_in[10];
  const int* l4  = (const int*)d_in[11];
  const int* ca1 = (const int*)d_in[12];
  const int* cb1 = (const int*)d_in[13];
  const int* ca2 = (const int*)d_in[14];
  const int* cb2 = (const int*)d_in[15];
  const int* ca3 = (const int*)d_in[16];
  const int* cb3 = (const int*)d_in[17];

  char* ws = (char*)d_ws;
  float4*         coefC  = (float4*)ws;                      // 108,544 B
  unsigned short* midx16 = (unsigned short*)(ws + 108544);   // 163,840 B
  _Float16*       mcoefh = (_Float16*)(ws + 108544 + 163840);// 573,440 B

  prep_all<<<307, 256, 0, stream>>>(w1, w2, w3, w4, fw1, fw2, fw3,
                                    ca1, cb1, ca2, cb2, ca3, cb3,
                                    coefC, midx16, mcoefh);
  mega<<<128, 1024, 0, stream>>>(x, coefC, l1, l2, l3, l4, midx16, mcoefh,
                                 (float*)d_out);
}